// Round 1
// baseline (563.791 us; speedup 1.0000x reference)
//
#include <hip/hip_runtime.h>
#include <math.h>

#define F 64
#define EPS 1e-5f

// Pass 1: per-node sum and sum-of-squares over the 64 features.
// One wave (64 lanes) per node; lane f reads x[node*64+f]; shuffle-reduce.
__global__ void node_sums_kernel(const float* __restrict__ x,
                                 float* __restrict__ rowsum,
                                 float* __restrict__ rowsumsq,
                                 int N) {
    int wave = (int)((blockIdx.x * (long long)blockDim.x + threadIdx.x) >> 6);
    int lane = threadIdx.x & 63;
    if (wave >= N) return;
    float v = x[wave * F + lane];
    float s = v;
    float s2 = v * v;
    #pragma unroll
    for (int off = 32; off > 0; off >>= 1) {
        s  += __shfl_down(s,  off, 64);
        s2 += __shfl_down(s2, off, 64);
    }
    if (lane == 0) {
        rowsum[wave]   = s;
        rowsumsq[wave] = s2;
    }
}

// Pass 2: per-edge scatter of degree, S1, S2 into destination node (row).
__global__ void edge_agg_kernel(const int* __restrict__ ei,
                                const float* __restrict__ rowsum,
                                const float* __restrict__ rowsumsq,
                                float* __restrict__ cnt,
                                float* __restrict__ s1,
                                float* __restrict__ s2,
                                int E) {
    int e = blockIdx.x * blockDim.x + threadIdx.x;
    if (e >= E) return;
    int r = ei[e];      // row
    int c = ei[E + e];  // col
    atomicAdd(&cnt[r], 1.0f);
    atomicAdd(&s1[r], rowsum[c]);
    atomicAdd(&s2[r], rowsumsq[c]);
}

// Pass 3: per-node mean and reciprocal std.
__global__ void node_stats_kernel(const float* __restrict__ cnt,
                                  const float* __restrict__ s1,
                                  const float* __restrict__ s2,
                                  float* __restrict__ meanA,
                                  float* __restrict__ rstdA,
                                  int N) {
    int i = blockIdx.x * blockDim.x + threadIdx.x;
    if (i >= N) return;
    float c  = cnt[i];
    float d  = fmaxf(c, 1.0f) * (float)F;   // denom * F
    float a  = s1[i];
    float m  = a / d;
    // var = (S2 - S1^2/d)/d  (exact when c>=1; S1==0 when c==0)
    float var = (s2[i] - a * a / d) / d;
    var = fmaxf(var, 0.0f);
    meanA[i] = m;
    rstdA[i] = 1.0f / sqrtf(var + EPS);
}

// Pass 4: the heavy pass. 16 threads per edge, each handles a float4 (4 feats).
// out[e,f] = gamma[f] * (x[col,f] - mean[row]) * rstd[row] + beta[f]
__global__ void edge_out_kernel(const float* __restrict__ x,
                                const int* __restrict__ ei,
                                const float* __restrict__ gamma,
                                const float* __restrict__ beta,
                                const float* __restrict__ meanA,
                                const float* __restrict__ rstdA,
                                float* __restrict__ out,
                                int E) {
    long long t = blockIdx.x * (long long)blockDim.x + threadIdx.x;
    int e = (int)(t >> 4);
    int v = (int)(t & 15);
    if (e >= E) return;
    int r = ei[e];
    int c = ei[E + e];
    float m = meanA[r];
    float s = rstdA[r];
    float4 xv = ((const float4*)x)[c * 16 + v];
    float4 gv = ((const float4*)gamma)[v];
    float4 bv = ((const float4*)beta)[v];
    float4 o;
    o.x = gv.x * ((xv.x - m) * s) + bv.x;
    o.y = gv.y * ((xv.y - m) * s) + bv.y;
    o.z = gv.z * ((xv.z - m) * s) + bv.z;
    o.w = gv.w * ((xv.w - m) * s) + bv.w;
    ((float4*)out)[e * 16 + v] = o;
}

extern "C" void kernel_launch(void* const* d_in, const int* in_sizes, int n_in,
                              void* d_out, int out_size, void* d_ws, size_t ws_size,
                              hipStream_t stream) {
    const float* x     = (const float*)d_in[0];
    const int*   ei    = (const int*)d_in[1];
    const float* gamma = (const float*)d_in[2];
    const float* beta  = (const float*)d_in[3];
    float* out = (float*)d_out;

    int N = in_sizes[0] / F;
    int E = in_sizes[1] / 2;

    // Workspace layout (floats): rowsum[N], rowsumsq[N], cnt[N], s1[N], s2[N], mean[N], rstd[N]
    float* ws       = (float*)d_ws;
    float* rowsum   = ws;
    float* rowsumsq = ws + (size_t)N;
    float* cnt      = ws + 2 * (size_t)N;
    float* s1       = ws + 3 * (size_t)N;
    float* s2       = ws + 4 * (size_t)N;
    float* meanA    = ws + 5 * (size_t)N;
    float* rstdA    = ws + 6 * (size_t)N;

    // zero the atomic accumulators (cnt, s1, s2 are contiguous)
    hipMemsetAsync(cnt, 0, 3 * (size_t)N * sizeof(float), stream);

    {   // pass 1: N waves, 4 waves per 256-thread block
        int blocks = (N + 3) / 4;
        node_sums_kernel<<<blocks, 256, 0, stream>>>(x, rowsum, rowsumsq, N);
    }
    {   // pass 2
        int blocks = (E + 255) / 256;
        edge_agg_kernel<<<blocks, 256, 0, stream>>>(ei, rowsum, rowsumsq, cnt, s1, s2, E);
    }
    {   // pass 3
        int blocks = (N + 255) / 256;
        node_stats_kernel<<<blocks, 256, 0, stream>>>(cnt, s1, s2, meanA, rstdA, N);
    }
    {   // pass 4: 16 threads per edge
        long long total = (long long)E * 16;
        int blocks = (int)((total + 255) / 256);
        edge_out_kernel<<<blocks, 256, 0, stream>>>(x, ei, gamma, beta, meanA, rstdA, out, E);
    }
}

// Round 2
// 546.024 us; speedup vs baseline: 1.0325x; 1.0325x over previous
//
#include <hip/hip_runtime.h>
#include <math.h>

#define F 64
#define EPS 1e-5f

// Pass 1: per-node sum and sum-of-squares over the 64 features.
// One wave (64 lanes) per node; lane f reads x[node*64+f]; shuffle-reduce.
__global__ void node_sums_kernel(const float* __restrict__ x,
                                 float* __restrict__ rowsum,
                                 float* __restrict__ rowsumsq,
                                 int N) {
    int wave = (int)((blockIdx.x * (long long)blockDim.x + threadIdx.x) >> 6);
    int lane = threadIdx.x & 63;
    if (wave >= N) return;
    float v = x[wave * F + lane];
    float s = v;
    float s2 = v * v;
    #pragma unroll
    for (int off = 32; off > 0; off >>= 1) {
        s  += __shfl_down(s,  off, 64);
        s2 += __shfl_down(s2, off, 64);
    }
    if (lane == 0) {
        rowsum[wave]   = s;
        rowsumsq[wave] = s2;
    }
}

// Pass 2: per-edge scatter of degree, S1, S2 into destination node (row).
// CRITICAL: unsafeAtomicAdd -> native global_atomic_add_f32 (no-return).
// Plain atomicAdd(float*) lowers to a CAS loop on gfx9 — retry storms under
// the avg-25-way contention here. cnt uses native int atomics.
__global__ void edge_agg_kernel(const int* __restrict__ ei,
                                const float* __restrict__ rowsum,
                                const float* __restrict__ rowsumsq,
                                int* __restrict__ cnt,
                                float* __restrict__ s1,
                                float* __restrict__ s2,
                                int E) {
    int e = blockIdx.x * blockDim.x + threadIdx.x;
    if (e >= E) return;
    int r = ei[e];      // row
    int c = ei[E + e];  // col
    atomicAdd(&cnt[r], 1);
    unsafeAtomicAdd(&s1[r], rowsum[c]);
    unsafeAtomicAdd(&s2[r], rowsumsq[c]);
}

// Pass 3: per-node mean and reciprocal std.
__global__ void node_stats_kernel(const int* __restrict__ cnt,
                                  const float* __restrict__ s1,
                                  const float* __restrict__ s2,
                                  float* __restrict__ meanA,
                                  float* __restrict__ rstdA,
                                  int N) {
    int i = blockIdx.x * blockDim.x + threadIdx.x;
    if (i >= N) return;
    float c  = (float)cnt[i];
    float d  = fmaxf(c, 1.0f) * (float)F;   // denom * F
    float a  = s1[i];
    float m  = a / d;
    // var = (S2 - S1^2/d)/d  (exact when c>=1; S1==0 when c==0)
    float var = (s2[i] - a * a / d) / d;
    var = fmaxf(var, 0.0f);
    meanA[i] = m;
    rstdA[i] = 1.0f / sqrtf(var + EPS);
}

// Pass 4: the heavy pass. 16 threads per edge, each handles a float4 (4 feats).
// out[e,f] = gamma[f] * (x[col,f] - mean[row]) * rstd[row] + beta[f]
__global__ void edge_out_kernel(const float* __restrict__ x,
                                const int* __restrict__ ei,
                                const float* __restrict__ gamma,
                                const float* __restrict__ beta,
                                const float* __restrict__ meanA,
                                const float* __restrict__ rstdA,
                                float* __restrict__ out,
                                int E) {
    long long t = blockIdx.x * (long long)blockDim.x + threadIdx.x;
    int e = (int)(t >> 4);
    int v = (int)(t & 15);
    if (e >= E) return;
    int r = ei[e];
    int c = ei[E + e];
    float m = meanA[r];
    float s = rstdA[r];
    float4 xv = ((const float4*)x)[c * 16 + v];
    float4 gv = ((const float4*)gamma)[v];
    float4 bv = ((const float4*)beta)[v];
    float4 o;
    o.x = gv.x * ((xv.x - m) * s) + bv.x;
    o.y = gv.y * ((xv.y - m) * s) + bv.y;
    o.z = gv.z * ((xv.z - m) * s) + bv.z;
    o.w = gv.w * ((xv.w - m) * s) + bv.w;
    ((float4*)out)[e * 16 + v] = o;
}

extern "C" void kernel_launch(void* const* d_in, const int* in_sizes, int n_in,
                              void* d_out, int out_size, void* d_ws, size_t ws_size,
                              hipStream_t stream) {
    const float* x     = (const float*)d_in[0];
    const int*   ei    = (const int*)d_in[1];
    const float* gamma = (const float*)d_in[2];
    const float* beta  = (const float*)d_in[3];
    float* out = (float*)d_out;

    int N = in_sizes[0] / F;
    int E = in_sizes[1] / 2;

    // Workspace layout (floats): rowsum[N], rowsumsq[N], cnt[N](int), s1[N], s2[N], mean[N], rstd[N]
    float* ws       = (float*)d_ws;
    float* rowsum   = ws;
    float* rowsumsq = ws + (size_t)N;
    int*   cnt      = (int*)(ws + 2 * (size_t)N);
    float* s1       = ws + 3 * (size_t)N;
    float* s2       = ws + 4 * (size_t)N;
    float* meanA    = ws + 5 * (size_t)N;
    float* rstdA    = ws + 6 * (size_t)N;

    // zero the atomic accumulators (cnt, s1, s2 are contiguous)
    hipMemsetAsync(cnt, 0, 3 * (size_t)N * sizeof(float), stream);

    {   // pass 1: N waves, 4 waves per 256-thread block
        int blocks = (N + 3) / 4;
        node_sums_kernel<<<blocks, 256, 0, stream>>>(x, rowsum, rowsumsq, N);
    }
    {   // pass 2
        int blocks = (E + 255) / 256;
        edge_agg_kernel<<<blocks, 256, 0, stream>>>(ei, rowsum, rowsumsq, cnt, s1, s2, E);
    }
    {   // pass 3
        int blocks = (N + 255) / 256;
        node_stats_kernel<<<blocks, 256, 0, stream>>>(cnt, s1, s2, meanA, rstdA, N);
    }
    {   // pass 4: 16 threads per edge
        long long total = (long long)E * 16;
        int blocks = (int)((total + 255) / 256);
        edge_out_kernel<<<blocks, 256, 0, stream>>>(x, ei, gamma, beta, meanA, rstdA, out, E);
    }
}